// Round 21
// baseline (255.520 us; speedup 1.0000x reference)
//
#include <hip/hip_runtime.h>
#include <stdint.h>

#define F_IN   22000
#define B_SZ   4096
#define T_STEPS 100
#define NSPLIT 16
#define NCHUNK 22
#define KSPAN  (NCHUNK * 64)      // 1408; 16*1408 = 22528 >= 22000
#define ACC_STRIDE 104
#define PART_BYTES ((size_t)NSPLIT * B_SZ * ACC_STRIDE * 4)  // 27,262,976
#define BIMG_BYTES 28672          // 112 cols * 64 k * 2B * (hi+lo), XOR-swizzled rows
#define BIMG_HALF  14336
#define W1IMG_BYTES ((size_t)NSPLIT * NCHUNK * BIMG_BYTES)   // 10,092,544
#define WRIMG_BYTES (128 * 1024)
#define LOG2E  1.44269504f
#define LOG2E2 2.88539008f

typedef float f32x4 __attribute__((ext_vector_type(4)));
typedef short s16x8 __attribute__((ext_vector_type(8)));

__device__ inline unsigned short f2bf(float f){
  unsigned u = __builtin_bit_cast(unsigned, f);
  u += 0x7FFFu + ((u >> 16) & 1u);          // round-to-nearest-even
  return (unsigned short)(u >> 16);
}
__device__ inline float bf2f(unsigned short h){
  return __builtin_bit_cast(float, ((unsigned)h) << 16);
}
__device__ inline float exp2f_(float x){
  float r; asm("v_exp_f32 %0, %1" : "=v"(r) : "v"(x)); return r;
}
__device__ inline float exp2n_(float x){   // exp2(-x), negate folded into src modifier
  float r; asm("v_exp_f32 %0, -%1" : "=v"(r) : "v"(x)); return r;
}

// ---------------- fused prep: W1 swizzled image | Wr fragment image (pre-scaled) ----------------
// blocks [0,352): w1img  |  [352,384): wrimg
__global__ __launch_bounds__(256) void k_prep(const float* __restrict__ W1,
                                              const float* __restrict__ Wr,
                                              char* __restrict__ img,
                                              char* __restrict__ wrimg){
  __shared__ float tile[64][129];
  int b = blockIdx.x, tid = threadIdx.x;
  if (b < NSPLIT * NCHUNK){
    int ch = b % NCHUNK, s = b / NCHUNK;
    int k0 = s * KSPAN + ch * 64;
    char* base = img + ((size_t)(s * NCHUNK + ch)) * BIMG_BYTES;
    for (int idx = tid; idx < 64 * 128; idx += 256){
      int k = idx >> 7, c = idx & 127;
      float v = 0.f;
      if (c < 100 && (k0 + k) < F_IN) v = W1[(size_t)(k0 + k) * 100 + c];
      tile[k][c] = v;
    }
    __syncthreads();
    #pragma unroll
    for (int q = 0; q < 4; ++q){
      int task = q * 256 + tid;
      if (task < 896){
        int p  = task * 16;
        int c  = p >> 7;
        int k8 = ((p >> 4) & 7) ^ (c & 7);
        unsigned hw[4], lw[4];
        #pragma unroll
        for (int jj = 0; jj < 4; ++jj){
          float v0 = tile[k8 * 8 + jj * 2][c];
          float v1 = tile[k8 * 8 + jj * 2 + 1][c];
          unsigned short h0 = f2bf(v0), l0 = f2bf(v0 - bf2f(h0));
          unsigned short h1 = f2bf(v1), l1 = f2bf(v1 - bf2f(h1));
          hw[jj] = (unsigned)h0 | ((unsigned)h1 << 16);
          lw[jj] = (unsigned)l0 | ((unsigned)l1 << 16);
        }
        *(uint4*)(base + p)             = make_uint4(hw[0], hw[1], hw[2], hw[3]);
        *(uint4*)(base + BIMG_HALF + p) = make_uint4(lw[0], lw[1], lw[2], lw[3]);
      }
    }
  } else {
    int gid = (b - NSPLIT * NCHUNK) * 256 + tid;   // 0..8191
    int lane = gid & 63, slot = gid >> 6;
    int kk = slot & 3, G = (slot >> 2) & 3, w = slot >> 4;
    int oct = lane >> 4, lr = lane & 15;
    int col = G * 128 + w * 16 + lr;
    float sg = (G == 2) ? LOG2E2 : LOG2E;
    unsigned pk[4];
    #pragma unroll
    for (int jj = 0; jj < 4; ++jj){
      float v0 = Wr[(size_t)(kk * 32 + oct * 8 + jj * 2)     * 512 + col] * sg;
      float v1 = Wr[(size_t)(kk * 32 + oct * 8 + jj * 2 + 1) * 512 + col] * sg;
      pk[jj] = (unsigned)f2bf(v0) | ((unsigned)f2bf(v1) << 16);
    }
    *(uint4*)(wrimg + (size_t)gid * 16) = make_uint4(pk[0], pk[1], pk[2], pk[3]);
  }
}

// ---- dense: M=64/block, single 28KB LDS buf, 4 blocks/CU, XCD-pinned; A prefetched 4 chunks deep ----
__global__ __launch_bounds__(256, 4) void k_dense(const float* __restrict__ x,
                                                  const char* __restrict__ img,
                                                  float* __restrict__ part){
  __shared__ char Bb[BIMG_BYTES];
  int tid = threadIdx.x;
  int lane = tid & 63, w = tid >> 6;           // w in [0,4)
  int r = lane & 15, oct = lane >> 4;
  int s = blockIdx.x;                          // split index (x-fastest => XCD-pinned, s%8)
  int brow = blockIdx.y * 64;
  int arow = brow + w * 16 + r;
  const float* xrow = x + (size_t)arow * F_IN;
  const char* isrc = img + (size_t)s * NCHUNK * BIMG_BYTES;
  int kbase = s * KSPAN;

  f32x4 acc[7];
  #pragma unroll
  for (int i = 0; i < 7; ++i) acc[i] = (f32x4)0.f;

#define ALOADM(CH, A0, A1, A2, A3) do{                                       \
    int k0_ = kbase + (CH) * 64;                                             \
    int ka0_ = k0_ + oct * 8;                                                \
    int ka1_ = k0_ + 32 + oct * 8;                                           \
    A0 = make_float4(0.f,0.f,0.f,0.f); A1 = A0; A2 = A0; A3 = A0;            \
    if (ka0_ < F_IN){ A0 = *(const float4*)(xrow + ka0_);                    \
                      A1 = *(const float4*)(xrow + ka0_ + 4); }              \
    if (ka1_ < F_IN){ A2 = *(const float4*)(xrow + ka1_);                    \
                      A3 = *(const float4*)(xrow + ka1_ + 4); }              \
  }while(0)

#define STAGEM(CH) do{                                                       \
    const char* src_ = isrc + (size_t)(CH) * BIMG_BYTES;                     \
    _Pragma("unroll")                                                        \
    for (int i_ = 0; i_ < 7; ++i_){                                          \
      int seg_ = i_ * 4 + w;                                                 \
      __builtin_amdgcn_global_load_lds(                                      \
        (const __attribute__((address_space(1))) void*)(src_ + seg_ * 1024 + lane * 16), \
        (__attribute__((address_space(3))) void*)(Bb + seg_ * 1024), 16, 0, 0); \
    }                                                                        \
  }while(0)

#define COMPUTEM(A0, A1, A2, A3) do{                                         \
    float va_[16] = {A0.x,A0.y,A0.z,A0.w, A1.x,A1.y,A1.z,A1.w,               \
                     A2.x,A2.y,A2.z,A2.w, A3.x,A3.y,A3.z,A3.w};              \
    s16x8 ah0_, al0_, ah1_, al1_;                                            \
    _Pragma("unroll")                                                        \
    for (int j_ = 0; j_ < 8; ++j_){                                          \
      unsigned short h_ = f2bf(va_[j_]);                                     \
      ah0_[j_] = (short)h_; al0_[j_] = (short)f2bf(va_[j_] - bf2f(h_));      \
    }                                                                        \
    _Pragma("unroll")                                                        \
    for (int j_ = 0; j_ < 8; ++j_){                                          \
      unsigned short h_ = f2bf(va_[8 + j_]);                                 \
      ah1_[j_] = (short)h_; al1_[j_] = (short)f2bf(va_[8 + j_] - bf2f(h_));  \
    }                                                                        \
    _Pragma("unroll")                                                        \
    for (int ct_ = 0; ct_ < 7; ++ct_){                                       \
      int c_ = ct_ * 16 + r;                                                 \
      int byte0_ = ((c_ * 128 + oct * 16) ^ ((c_ & 7) << 4));                \
      int byte1_ = ((c_ * 128 + 64 + oct * 16) ^ ((c_ & 7) << 4));           \
      s16x8 bh0_ = *(s16x8*)(Bb + byte0_);                                   \
      s16x8 bl0_ = *(s16x8*)(Bb + BIMG_HALF + byte0_);                       \
      s16x8 bh1_ = *(s16x8*)(Bb + byte1_);                                   \
      s16x8 bl1_ = *(s16x8*)(Bb + BIMG_HALF + byte1_);                       \
      acc[ct_] = __builtin_amdgcn_mfma_f32_16x16x32_bf16(ah0_, bh0_, acc[ct_], 0, 0, 0); \
      acc[ct_] = __builtin_amdgcn_mfma_f32_16x16x32_bf16(ah0_, bl0_, acc[ct_], 0, 0, 0); \
      acc[ct_] = __builtin_amdgcn_mfma_f32_16x16x32_bf16(al0_, bh0_, acc[ct_], 0, 0, 0); \
      acc[ct_] = __builtin_amdgcn_mfma_f32_16x16x32_bf16(ah1_, bh1_, acc[ct_], 0, 0, 0); \
      acc[ct_] = __builtin_amdgcn_mfma_f32_16x16x32_bf16(ah1_, bl1_, acc[ct_], 0, 0, 0); \
      acc[ct_] = __builtin_amdgcn_mfma_f32_16x16x32_bf16(al1_, bh1_, acc[ct_], 0, 0, 0); \
    }                                                                        \
  }while(0)

  // A register sets for 4-deep prefetch (named, rule #20)
  float4 p00, p01, p02, p03, p10, p11, p12, p13;
  float4 p20, p21, p22, p23, p30, p31, p32, p33;

  // 5 full groups of 4 chunks (0..19)
  for (int g = 0; g + 4 <= NCHUNK; g += 4){
    ALOADM(g + 0, p00, p01, p02, p03);
    ALOADM(g + 1, p10, p11, p12, p13);
    ALOADM(g + 2, p20, p21, p22, p23);
    ALOADM(g + 3, p30, p31, p32, p33);
    STAGEM(g + 0);
    __syncthreads();                 // drains A(g..g+3) + B(g) together
    COMPUTEM(p00, p01, p02, p03);
    __syncthreads();
    STAGEM(g + 1);
    __syncthreads();                 // short drain: B only (L2)
    COMPUTEM(p10, p11, p12, p13);
    __syncthreads();
    STAGEM(g + 2);
    __syncthreads();
    COMPUTEM(p20, p21, p22, p23);
    __syncthreads();
    STAGEM(g + 3);
    __syncthreads();
    COMPUTEM(p30, p31, p32, p33);
    __syncthreads();
  }
  // tail: chunks 20, 21
  ALOADM(20, p00, p01, p02, p03);
  ALOADM(21, p10, p11, p12, p13);
  STAGEM(20);
  __syncthreads();
  COMPUTEM(p00, p01, p02, p03);
  __syncthreads();
  STAGEM(21);
  __syncthreads();
  COMPUTEM(p10, p11, p12, p13);
  __syncthreads();

#undef ALOADM
#undef STAGEM
#undef COMPUTEM

  float* pbase = part + (size_t)s * B_SZ * ACC_STRIDE;
  #pragma unroll
  for (int ct = 0; ct < 7; ++ct){
    int col = ct * 16 + r;
    if (col < 100){
      #pragma unroll
      for (int reg = 0; reg < 4; ++reg){
        int orow = brow + w * 16 + oct * 4 + reg;
        pbase[(size_t)orow * ACC_STRIDE + col] = acc[ct][reg];
      }
    }
  }
}

// ---- LSTM: 16 rows/block, 256 blocks, 512 thr / 8 waves; conflict-free swizzle, exp2 gates ----
// swizzle S(row) = 2*((row>>2 + (row&3)) & 3) + (row>>2 & 1); byte ^= S<<4 (bijective per row)
__global__ __launch_bounds__(512, 2) void k_lstm(const float* __restrict__ part,
                                                 const float* __restrict__ b1,
                                                 const float* __restrict__ Wk,
                                                 const char* __restrict__ wrimg,
                                                 const float* __restrict__ bl,
                                                 const float* __restrict__ W2,
                                                 const float* __restrict__ b2,
                                                 float* __restrict__ out){
  __shared__ unsigned short hbuf[2][16 * 128]; // bf16 h, S-swizzled rows of 256B
  __shared__ float dld[16][ACC_STRIDE];
  __shared__ float hf[16][132];
  int tid = threadIdx.x;
  int lane = tid & 63, w = tid >> 6;           // w in [0,8)
  int oct = lane >> 4, lr = lane & 15;
  int brow = blockIdx.x * 16;

  for (int i = tid; i < 2048; i += 512) hbuf[0][i] = 0;
  for (int i = tid; i < 16 * T_STEPS; i += 512){
    int r = i / T_STEPS, t = i % T_STEPS;
    float v = b1[t];
    #pragma unroll
    for (int s = 0; s < NSPLIT; ++s)
      v += part[((size_t)(s * B_SZ + brow + r)) * ACC_STRIDE + t];
    dld[r][t] = v;
  }

  float wkv[4], blv[4];
  s16x8 bfrag[4][4];
  #pragma unroll
  for (int G = 0; G < 4; ++G){
    int col = G * 128 + w * 16 + lr;
    float sg = (G == 2) ? LOG2E2 : LOG2E;
    wkv[G] = Wk[col] * sg;
    blv[G] = bl[col] * sg;
    #pragma unroll
    for (int kk = 0; kk < 4; ++kk){
      bfrag[G][kk] = *(const s16x8*)(wrimg +
          ((size_t)(((w * 4 + G) * 4 + kk) * 64 + lane)) * 16);
    }
  }
  float cst[4];
  #pragma unroll
  for (int reg = 0; reg < 4; ++reg) cst[reg] = 0.f;
  int sxl = (2 * (((lr >> 2) + (lr & 3)) & 3) + ((lr >> 2) & 1)) << 4;  // S(lr)<<4
  int sxw[4];
  #pragma unroll
  for (int reg = 0; reg < 4; ++reg)
    sxw[reg] = (2 * ((oct + reg) & 3) + (oct & 1)) << 4;                // S(oct*4+reg)<<4
  __syncthreads();

  for (int t = 0; t < T_STEPS; ++t){
    int cur = t & 1;
    f32x4 accA[4], accB[4];
    float dv[4];
    #pragma unroll
    for (int reg = 0; reg < 4; ++reg) dv[reg] = dld[oct * 4 + reg][t];
    #pragma unroll
    for (int G = 0; G < 4; ++G){
      #pragma unroll
      for (int reg = 0; reg < 4; ++reg){
        accA[G][reg] = dv[reg] * wkv[G] + blv[G];
        accB[G][reg] = 0.f;
      }
    }
    #pragma unroll
    for (int kk = 0; kk < 4; ++kk){
      int abyte = (lr * 256 + kk * 64 + oct * 16) ^ sxl;
      s16x8 a = *(s16x8*)((char*)hbuf[cur] + abyte);
      if (kk < 2){
        #pragma unroll
        for (int G = 0; G < 4; ++G)
          accA[G] = __builtin_amdgcn_mfma_f32_16x16x32_bf16(a, bfrag[G][kk], accA[G], 0, 0, 0);
      } else {
        #pragma unroll
        for (int G = 0; G < 4; ++G)
          accB[G] = __builtin_amdgcn_mfma_f32_16x16x32_bf16(a, bfrag[G][kk], accB[G], 0, 0, 0);
      }
    }
    #pragma unroll
    for (int reg = 0; reg < 4; ++reg){
      float z0 = accA[0][reg] + accB[0][reg];
      float z1 = accA[1][reg] + accB[1][reg];
      float z2 = accA[2][reg] + accB[2][reg];
      float z3 = accA[3][reg] + accB[3][reg];
      float iv = __builtin_amdgcn_rcpf(1.f + exp2n_(z0));
      float fv = __builtin_amdgcn_rcpf(1.f + exp2n_(z1));
      float gv = 1.f - 2.f * __builtin_amdgcn_rcpf(exp2f_(z2) + 1.f);
      float ov = __builtin_amdgcn_rcpf(1.f + exp2n_(z3));
      float cv = fv * cst[reg] + iv * gv;
      cst[reg] = cv;
      float tc = 1.f - 2.f * __builtin_amdgcn_rcpf(exp2f_(cv * LOG2E2) + 1.f);
      float hv = ov * tc;
      int row = oct * 4 + reg;
      int col = w * 16 + lr;
      int byte = (row * 256 + col * 2) ^ sxw[reg];
      *(unsigned short*)((char*)hbuf[cur ^ 1] + byte) = f2bf(hv);
      if (t == T_STEPS - 1) hf[row][col] = hv;
    }
    __syncthreads();
  }

  if (tid < 64){
    int row = tid >> 2, cl = tid & 3;
    float a = b2[cl];
    #pragma unroll 8
    for (int j = 0; j < 128; ++j) a += hf[row][j] * W2[j * 4 + cl];
    float m = fmaxf(a, __shfl_xor(a, 1));
    m = fmaxf(m, __shfl_xor(m, 2));
    float e = __expf(a - m);
    float se = e + __shfl_xor(e, 1);
    se += __shfl_xor(se, 2);
    out[(size_t)(brow + row) * 4 + cl] = e * __builtin_amdgcn_rcpf(se);
  }
}

extern "C" void kernel_launch(void* const* d_in, const int* in_sizes, int n_in,
                              void* d_out, int out_size, void* d_ws, size_t ws_size,
                              hipStream_t stream){
  const float* x  = (const float*)d_in[0];
  const float* W1 = (const float*)d_in[1];
  const float* b1 = (const float*)d_in[2];
  const float* Wk = (const float*)d_in[3];
  const float* Wr = (const float*)d_in[4];
  const float* bl = (const float*)d_in[5];
  const float* W2 = (const float*)d_in[6];
  const float* b2 = (const float*)d_in[7];
  float* out = (float*)d_out;

  // ws: part f32[16][4096][104] | W1 image | Wr image
  char* ws = (char*)d_ws;
  float* part  = (float*)ws;
  char*  img   = ws + PART_BYTES;
  char*  wrimg = ws + PART_BYTES + W1IMG_BYTES;

  k_prep<<<NSPLIT * NCHUNK + 32, 256, 0, stream>>>(W1, Wr, img, wrimg);
  k_dense<<<dim3(NSPLIT, B_SZ / 64), 256, 0, stream>>>(x, img, part);
  k_lstm<<<B_SZ / 16, 512, 0, stream>>>(part, b1, Wk, wrimg, bl, W2, b2, out);
}

// Round 22
// 226.263 us; speedup vs baseline: 1.1293x; 1.1293x over previous
//
#include <hip/hip_runtime.h>
#include <stdint.h>

#define F_IN   22000
#define B_SZ   4096
#define T_STEPS 100
#define NSPLIT 16
#define NCHUNK 22
#define KSPAN  (NCHUNK * 64)      // 1408; 16*1408 = 22528 >= 22000
#define ACC_STRIDE 104
#define PART_BYTES ((size_t)NSPLIT * B_SZ * ACC_STRIDE * 4)  // 27,262,976
#define BIMG_BYTES 28672          // 112 cols * 64 k * 2B * (hi+lo), XOR-swizzled rows
#define BIMG_HALF  14336
#define W1IMG_BYTES ((size_t)NSPLIT * NCHUNK * BIMG_BYTES)   // 10,092,544
#define WRIMG_BYTES (128 * 1024)
#define LOG2E  1.44269504f
#define LOG2E2 2.88539008f

typedef float f32x4 __attribute__((ext_vector_type(4)));
typedef short s16x8 __attribute__((ext_vector_type(8)));

__device__ inline unsigned short f2bf(float f){
  unsigned u = __builtin_bit_cast(unsigned, f);
  u += 0x7FFFu + ((u >> 16) & 1u);          // round-to-nearest-even
  return (unsigned short)(u >> 16);
}
__device__ inline float bf2f(unsigned short h){
  return __builtin_bit_cast(float, ((unsigned)h) << 16);
}
__device__ inline float exp2f_(float x){
  float r; asm("v_exp_f32 %0, %1" : "=v"(r) : "v"(x)); return r;
}
__device__ inline float exp2n_(float x){   // exp2(-x), negate folded into src modifier
  float r; asm("v_exp_f32 %0, -%1" : "=v"(r) : "v"(x)); return r;
}

// ---------------- fused prep: W1 swizzled image | Wr fragment image (pre-scaled) ----------------
// blocks [0,352): w1img  |  [352,384): wrimg
__global__ __launch_bounds__(256) void k_prep(const float* __restrict__ W1,
                                              const float* __restrict__ Wr,
                                              char* __restrict__ img,
                                              char* __restrict__ wrimg){
  __shared__ float tile[64][129];
  int b = blockIdx.x, tid = threadIdx.x;
  if (b < NSPLIT * NCHUNK){
    int ch = b % NCHUNK, s = b / NCHUNK;
    int k0 = s * KSPAN + ch * 64;
    char* base = img + ((size_t)(s * NCHUNK + ch)) * BIMG_BYTES;
    for (int idx = tid; idx < 64 * 128; idx += 256){
      int k = idx >> 7, c = idx & 127;
      float v = 0.f;
      if (c < 100 && (k0 + k) < F_IN) v = W1[(size_t)(k0 + k) * 100 + c];
      tile[k][c] = v;
    }
    __syncthreads();
    #pragma unroll
    for (int q = 0; q < 4; ++q){
      int task = q * 256 + tid;
      if (task < 896){
        int p  = task * 16;
        int c  = p >> 7;
        int k8 = ((p >> 4) & 7) ^ (c & 7);
        unsigned hw[4], lw[4];
        #pragma unroll
        for (int jj = 0; jj < 4; ++jj){
          float v0 = tile[k8 * 8 + jj * 2][c];
          float v1 = tile[k8 * 8 + jj * 2 + 1][c];
          unsigned short h0 = f2bf(v0), l0 = f2bf(v0 - bf2f(h0));
          unsigned short h1 = f2bf(v1), l1 = f2bf(v1 - bf2f(h1));
          hw[jj] = (unsigned)h0 | ((unsigned)h1 << 16);
          lw[jj] = (unsigned)l0 | ((unsigned)l1 << 16);
        }
        *(uint4*)(base + p)             = make_uint4(hw[0], hw[1], hw[2], hw[3]);
        *(uint4*)(base + BIMG_HALF + p) = make_uint4(lw[0], lw[1], lw[2], lw[3]);
      }
    }
  } else {
    int gid = (b - NSPLIT * NCHUNK) * 256 + tid;   // 0..8191
    int lane = gid & 63, slot = gid >> 6;
    int kk = slot & 3, G = (slot >> 2) & 3, w = slot >> 4;
    int oct = lane >> 4, lr = lane & 15;
    int col = G * 128 + w * 16 + lr;
    float sg = (G == 2) ? LOG2E2 : LOG2E;
    unsigned pk[4];
    #pragma unroll
    for (int jj = 0; jj < 4; ++jj){
      float v0 = Wr[(size_t)(kk * 32 + oct * 8 + jj * 2)     * 512 + col] * sg;
      float v1 = Wr[(size_t)(kk * 32 + oct * 8 + jj * 2 + 1) * 512 + col] * sg;
      pk[jj] = (unsigned)f2bf(v0) | ((unsigned)f2bf(v1) << 16);
    }
    *(uint4*)(wrimg + (size_t)gid * 16) = make_uint4(pk[0], pk[1], pk[2], pk[3]);
  }
}

// ---- dense: M=64/block, single 28KB LDS buf, 4 blocks/CU; XCD-locality grid (s = blockIdx.x) ----
__global__ __launch_bounds__(256, 4) void k_dense(const float* __restrict__ x,
                                                  const char* __restrict__ img,
                                                  float* __restrict__ part){
  __shared__ char Bb[BIMG_BYTES];
  int tid = threadIdx.x;
  int lane = tid & 63, w = tid >> 6;           // w in [0,4)
  int r = lane & 15, oct = lane >> 4;
  int s = blockIdx.x;                          // split index (x-fastest => XCD-pinned)
  int brow = blockIdx.y * 64;
  int arow = brow + w * 16 + r;
  const float* xrow = x + (size_t)arow * F_IN;
  const char* isrc = img + (size_t)s * NCHUNK * BIMG_BYTES;
  int kbase = s * KSPAN;

  f32x4 acc[7];
  #pragma unroll
  for (int i = 0; i < 7; ++i) acc[i] = (f32x4)0.f;

  for (int ch = 0; ch < NCHUNK; ++ch){
    int k0 = kbase + ch * 64;
    int ka0 = k0 + oct * 8;
    int ka1 = k0 + 32 + oct * 8;
    float4 a0 = make_float4(0.f,0.f,0.f,0.f), a1 = a0, a2 = a0, a3 = a0;
    if (ka0 < F_IN){ a0 = *(const float4*)(xrow + ka0);
                     a1 = *(const float4*)(xrow + ka0 + 4); }
    if (ka1 < F_IN){ a2 = *(const float4*)(xrow + ka1);
                     a3 = *(const float4*)(xrow + ka1 + 4); }
    {
      const char* src = isrc + (size_t)ch * BIMG_BYTES;
      #pragma unroll
      for (int i = 0; i < 7; ++i){
        int seg = i * 4 + w;
        __builtin_amdgcn_global_load_lds(
          (const __attribute__((address_space(1))) void*)(src + seg * 1024 + lane * 16),
          (__attribute__((address_space(3))) void*)(Bb + seg * 1024), 16, 0, 0);
      }
    }
    __syncthreads();
    float va[16] = {a0.x,a0.y,a0.z,a0.w, a1.x,a1.y,a1.z,a1.w,
                    a2.x,a2.y,a2.z,a2.w, a3.x,a3.y,a3.z,a3.w};
    s16x8 ah0, al0, ah1, al1;
    #pragma unroll
    for (int j = 0; j < 8; ++j){
      unsigned short h = f2bf(va[j]);
      ah0[j] = (short)h; al0[j] = (short)f2bf(va[j] - bf2f(h));
    }
    #pragma unroll
    for (int j = 0; j < 8; ++j){
      unsigned short h = f2bf(va[8 + j]);
      ah1[j] = (short)h; al1[j] = (short)f2bf(va[8 + j] - bf2f(h));
    }
    #pragma unroll
    for (int ct = 0; ct < 7; ++ct){
      int c = ct * 16 + r;
      int byte0 = ((c * 128 + oct * 16) ^ ((c & 7) << 4));
      int byte1 = ((c * 128 + 64 + oct * 16) ^ ((c & 7) << 4));
      s16x8 bh0 = *(s16x8*)(Bb + byte0);
      s16x8 bl0 = *(s16x8*)(Bb + BIMG_HALF + byte0);
      s16x8 bh1 = *(s16x8*)(Bb + byte1);
      s16x8 bl1 = *(s16x8*)(Bb + BIMG_HALF + byte1);
      acc[ct] = __builtin_amdgcn_mfma_f32_16x16x32_bf16(ah0, bh0, acc[ct], 0, 0, 0);
      acc[ct] = __builtin_amdgcn_mfma_f32_16x16x32_bf16(ah0, bl0, acc[ct], 0, 0, 0);
      acc[ct] = __builtin_amdgcn_mfma_f32_16x16x32_bf16(al0, bh0, acc[ct], 0, 0, 0);
      acc[ct] = __builtin_amdgcn_mfma_f32_16x16x32_bf16(ah1, bh1, acc[ct], 0, 0, 0);
      acc[ct] = __builtin_amdgcn_mfma_f32_16x16x32_bf16(ah1, bl1, acc[ct], 0, 0, 0);
      acc[ct] = __builtin_amdgcn_mfma_f32_16x16x32_bf16(al1, bh1, acc[ct], 0, 0, 0);
    }
    __syncthreads();
  }

  float* pbase = part + (size_t)s * B_SZ * ACC_STRIDE;
  #pragma unroll
  for (int ct = 0; ct < 7; ++ct){
    int col = ct * 16 + r;
    if (col < 100){
      #pragma unroll
      for (int reg = 0; reg < 4; ++reg){
        int orow = brow + w * 16 + oct * 4 + reg;
        pbase[(size_t)orow * ACC_STRIDE + col] = acc[ct][reg];
      }
    }
  }
}

// ---- LSTM: 16 rows/block, 256 blocks, 512 thr / 8 waves; conflict-free swizzle, exp2 gates ----
// swizzle S(row) = 2*((row>>2 + (row&3)) & 3) + (row>>2 & 1); byte ^= S<<4 (bijective per row)
__global__ __launch_bounds__(512, 2) void k_lstm(const float* __restrict__ part,
                                                 const float* __restrict__ b1,
                                                 const float* __restrict__ Wk,
                                                 const char* __restrict__ wrimg,
                                                 const float* __restrict__ bl,
                                                 const float* __restrict__ W2,
                                                 const float* __restrict__ b2,
                                                 float* __restrict__ out){
  __shared__ unsigned short hbuf[2][16 * 128]; // bf16 h, S-swizzled rows of 256B
  __shared__ float dld[16][ACC_STRIDE];
  __shared__ float hf[16][132];
  int tid = threadIdx.x;
  int lane = tid & 63, w = tid >> 6;           // w in [0,8)
  int oct = lane >> 4, lr = lane & 15;
  int brow = blockIdx.x * 16;

  for (int i = tid; i < 2048; i += 512) hbuf[0][i] = 0;
  for (int i = tid; i < 16 * T_STEPS; i += 512){
    int r = i / T_STEPS, t = i % T_STEPS;
    float v = b1[t];
    #pragma unroll
    for (int s = 0; s < NSPLIT; ++s)
      v += part[((size_t)(s * B_SZ + brow + r)) * ACC_STRIDE + t];
    dld[r][t] = v;
  }

  float wkv[4], blv[4];
  s16x8 bfrag[4][4];
  #pragma unroll
  for (int G = 0; G < 4; ++G){
    int col = G * 128 + w * 16 + lr;
    float sg = (G == 2) ? LOG2E2 : LOG2E;
    wkv[G] = Wk[col] * sg;
    blv[G] = bl[col] * sg;
    #pragma unroll
    for (int kk = 0; kk < 4; ++kk){
      bfrag[G][kk] = *(const s16x8*)(wrimg +
          ((size_t)(((w * 4 + G) * 4 + kk) * 64 + lane)) * 16);
    }
  }
  float cst[4];
  #pragma unroll
  for (int reg = 0; reg < 4; ++reg) cst[reg] = 0.f;
  int sxl = (2 * (((lr >> 2) + (lr & 3)) & 3) + ((lr >> 2) & 1)) << 4;  // S(lr)<<4
  int sxw[4];
  #pragma unroll
  for (int reg = 0; reg < 4; ++reg)
    sxw[reg] = (2 * ((oct + reg) & 3) + (oct & 1)) << 4;                // S(oct*4+reg)<<4
  __syncthreads();

  for (int t = 0; t < T_STEPS; ++t){
    int cur = t & 1;
    f32x4 accA[4], accB[4];
    float dv[4];
    #pragma unroll
    for (int reg = 0; reg < 4; ++reg) dv[reg] = dld[oct * 4 + reg][t];
    #pragma unroll
    for (int G = 0; G < 4; ++G){
      #pragma unroll
      for (int reg = 0; reg < 4; ++reg){
        accA[G][reg] = dv[reg] * wkv[G] + blv[G];
        accB[G][reg] = 0.f;
      }
    }
    #pragma unroll
    for (int kk = 0; kk < 4; ++kk){
      int abyte = (lr * 256 + kk * 64 + oct * 16) ^ sxl;
      s16x8 a = *(s16x8*)((char*)hbuf[cur] + abyte);
      if (kk < 2){
        #pragma unroll
        for (int G = 0; G < 4; ++G)
          accA[G] = __builtin_amdgcn_mfma_f32_16x16x32_bf16(a, bfrag[G][kk], accA[G], 0, 0, 0);
      } else {
        #pragma unroll
        for (int G = 0; G < 4; ++G)
          accB[G] = __builtin_amdgcn_mfma_f32_16x16x32_bf16(a, bfrag[G][kk], accB[G], 0, 0, 0);
      }
    }
    #pragma unroll
    for (int reg = 0; reg < 4; ++reg){
      float z0 = accA[0][reg] + accB[0][reg];
      float z1 = accA[1][reg] + accB[1][reg];
      float z2 = accA[2][reg] + accB[2][reg];
      float z3 = accA[3][reg] + accB[3][reg];
      float iv = __builtin_amdgcn_rcpf(1.f + exp2n_(z0));
      float fv = __builtin_amdgcn_rcpf(1.f + exp2n_(z1));
      float gv = 1.f - 2.f * __builtin_amdgcn_rcpf(exp2f_(z2) + 1.f);
      float ov = __builtin_amdgcn_rcpf(1.f + exp2n_(z3));
      float cv = fv * cst[reg] + iv * gv;
      cst[reg] = cv;
      float tc = 1.f - 2.f * __builtin_amdgcn_rcpf(exp2f_(cv * LOG2E2) + 1.f);
      float hv = ov * tc;
      int row = oct * 4 + reg;
      int col = w * 16 + lr;
      int byte = (row * 256 + col * 2) ^ sxw[reg];
      *(unsigned short*)((char*)hbuf[cur ^ 1] + byte) = f2bf(hv);
      if (t == T_STEPS - 1) hf[row][col] = hv;
    }
    __syncthreads();
  }

  if (tid < 64){
    int row = tid >> 2, cl = tid & 3;
    float a = b2[cl];
    #pragma unroll 8
    for (int j = 0; j < 128; ++j) a += hf[row][j] * W2[j * 4 + cl];
    float m = fmaxf(a, __shfl_xor(a, 1));
    m = fmaxf(m, __shfl_xor(m, 2));
    float e = __expf(a - m);
    float se = e + __shfl_xor(e, 1);
    se += __shfl_xor(se, 2);
    out[(size_t)(brow + row) * 4 + cl] = e * __builtin_amdgcn_rcpf(se);
  }
}

extern "C" void kernel_launch(void* const* d_in, const int* in_sizes, int n_in,
                              void* d_out, int out_size, void* d_ws, size_t ws_size,
                              hipStream_t stream){
  const float* x  = (const float*)d_in[0];
  const float* W1 = (const float*)d_in[1];
  const float* b1 = (const float*)d_in[2];
  const float* Wk = (const float*)d_in[3];
  const float* Wr = (const float*)d_in[4];
  const float* bl = (const float*)d_in[5];
  const float* W2 = (const float*)d_in[6];
  const float* b2 = (const float*)d_in[7];
  float* out = (float*)d_out;

  // ws: part f32[16][4096][104] | W1 image | Wr image
  char* ws = (char*)d_ws;
  float* part  = (float*)ws;
  char*  img   = ws + PART_BYTES;
  char*  wrimg = ws + PART_BYTES + W1IMG_BYTES;

  k_prep<<<NSPLIT * NCHUNK + 32, 256, 0, stream>>>(W1, Wr, img, wrimg);
  k_dense<<<dim3(NSPLIT, B_SZ / 64), 256, 0, stream>>>(x, img, part);
  k_lstm<<<B_SZ / 16, 512, 0, stream>>>(part, b1, Wk, wrimg, bl, W2, b2, out);
}